// Round 4
// baseline (6344.659 us; speedup 1.0000x reference)
//
#include <hip/hip_runtime.h>
#include <math.h>

#define SEQ     2048
#define DMODEL  1024
#define DINNER  2048
#define DSTATE  64
#define DTRANK  64
#define NLAYERS 4
#define XDBW    192
#define MROWS   8192   // 4*SEQ

typedef __attribute__((ext_vector_type(8))) short bf16x8;
typedef __attribute__((ext_vector_type(4))) float f32x4;

__device__ __forceinline__ float nanfix(float x) {
    if (x != x) return 0.f;
    return fminf(fmaxf(x, -3.402823466e38f), 3.402823466e38f);
}
__device__ __forceinline__ float silu(float x) { return x / (1.f + __expf(-x)); }
__device__ __forceinline__ float bf2f(unsigned short u) {
    return __uint_as_float((unsigned int)u << 16);
}
__device__ __forceinline__ unsigned short f2bf(float f) {
    unsigned int u = __float_as_uint(f);
    u += 0x7FFFu + ((u >> 16) & 1u);
    return (unsigned short)(u >> 16);
}
__device__ __forceinline__ void unpack8(uint4 r, float* f) {
    f[0] = __uint_as_float(r.x << 16); f[1] = __uint_as_float(r.x & 0xFFFF0000u);
    f[2] = __uint_as_float(r.y << 16); f[3] = __uint_as_float(r.y & 0xFFFF0000u);
    f[4] = __uint_as_float(r.z << 16); f[5] = __uint_as_float(r.z & 0xFFFF0000u);
    f[6] = __uint_as_float(r.w << 16); f[7] = __uint_as_float(r.w & 0xFFFF0000u);
}
__device__ __forceinline__ uint4 pack8(const float* f) {
    uint4 r;
    r.x = (unsigned int)f2bf(f[0]) | ((unsigned int)f2bf(f[1]) << 16);
    r.y = (unsigned int)f2bf(f[2]) | ((unsigned int)f2bf(f[3]) << 16);
    r.z = (unsigned int)f2bf(f[4]) | ((unsigned int)f2bf(f[5]) << 16);
    r.w = (unsigned int)f2bf(f[6]) | ((unsigned int)f2bf(f[7]) << 16);
    return r;
}

#define GLDS16(g, l) __builtin_amdgcn_global_load_lds( \
    (const __attribute__((address_space(1))) void*)(g), \
    (__attribute__((address_space(3))) void*)(l), 16, 0, 0)

// ---------------- bf16 MFMA GEMM: C[M,N] = A[M,K] * W[N,K]^T ----------------
template<int EPI>
__global__ __launch_bounds__(256)
void mgemm_kernel(void* __restrict__ Cp, const unsigned short* __restrict__ A,
                  const unsigned short* __restrict__ W, int N, int K, int ldc)
{
    __shared__ unsigned short As[128 * 32];
    __shared__ unsigned short Bs[128 * 32];
    const int tid  = threadIdx.x;
    const int lane = tid & 63;
    const int wv   = tid >> 6;
    const int wr   = (wv >> 1) * 64;
    const int wc   = (wv & 1) * 64;
    const int bm   = blockIdx.x * 128;
    const int bn   = blockIdx.y * 128;

    const int fr = lane & 15;
    const int kq = (lane >> 4) * 8;

    const int g_row = wv * 16 + (lane >> 2);
    const int g_col = (lane & 3) * 8;
    const unsigned short* a0 = A + (size_t)(bm + g_row) * K + g_col;
    const unsigned short* a1 = A + (size_t)(bm + 64 + g_row) * K + g_col;
    const unsigned short* b0 = W + (size_t)(bn + g_row) * K + g_col;
    const unsigned short* b1 = W + (size_t)(bn + 64 + g_row) * K + g_col;
    unsigned short* lA0 = &As[wv * 512];
    unsigned short* lA1 = &As[2048 + wv * 512];
    unsigned short* lB0 = &Bs[wv * 512];
    unsigned short* lB1 = &Bs[2048 + wv * 512];

    f32x4 acc[4][4];
    #pragma unroll
    for (int i = 0; i < 4; i++)
        #pragma unroll
        for (int j = 0; j < 4; j++) acc[i][j] = (f32x4){0.f, 0.f, 0.f, 0.f};

    for (int k0 = 0; k0 < K; k0 += 32) {
        GLDS16(a0 + k0, lA0);
        GLDS16(a1 + k0, lA1);
        GLDS16(b0 + k0, lB0);
        GLDS16(b1 + k0, lB1);
        __syncthreads();

        bf16x8 af[4], bfv[4];
        #pragma unroll
        for (int mi = 0; mi < 4; mi++)
            af[mi] = *(const bf16x8*)&As[(wr + mi * 16 + fr) * 32 + kq];
        #pragma unroll
        for (int ni = 0; ni < 4; ni++)
            bfv[ni] = *(const bf16x8*)&Bs[(wc + ni * 16 + fr) * 32 + kq];
        #pragma unroll
        for (int mi = 0; mi < 4; mi++)
            #pragma unroll
            for (int ni = 0; ni < 4; ni++)
                acc[mi][ni] = __builtin_amdgcn_mfma_f32_16x16x32_bf16(
                    af[mi], bfv[ni], acc[mi][ni], 0, 0, 0);
        __syncthreads();
    }

    const int orow = (lane >> 4) * 4;
    #pragma unroll
    for (int mi = 0; mi < 4; mi++) {
        #pragma unroll
        for (int r = 0; r < 4; r++) {
            const int row = bm + wr + mi * 16 + orow + r;
            #pragma unroll
            for (int ni = 0; ni < 4; ni++) {
                const int col = bn + wc + ni * 16 + fr;
                const float v = acc[mi][ni][r];
                if (EPI == 0) {
                    ((unsigned short*)Cp)[(size_t)row * ldc + col] = f2bf(v);
                } else if (EPI == 1) {
                    if (col < N) ((float*)Cp)[(size_t)row * ldc + col] = v;
                } else {
                    float* C = (float*)Cp;
                    const size_t o = (size_t)row * ldc + col;
                    C[o] = nanfix(C[o] + nanfix(v));
                }
            }
        }
    }
}

// ---------------- fp32 vector GEMM (delta projection, K=64), softplus, bf16 out ----------------
__global__ __launch_bounds__(256)
void gemm_delta_kernel(unsigned short* __restrict__ C, const float* __restrict__ A,
                       const float* __restrict__ W, const float* __restrict__ bias,
                       int M, int N, int K, int lda, int ldc)
{
    __shared__ float As[16][128];
    __shared__ float Ws[16][128];
    const int tid  = threadIdx.x;
    const int bm   = blockIdx.x * 128;
    const int bn   = blockIdx.y * 128;
    const int tx   = tid & 15;
    const int ty   = tid >> 4;
    const int slot = tid & 3;
    const int row  = tid >> 2;

    float acc[8][8];
    #pragma unroll
    for (int i = 0; i < 8; i++)
        #pragma unroll
        for (int j = 0; j < 8; j++) acc[i][j] = 0.f;

    for (int k0 = 0; k0 < K; k0 += 16) {
        float4 a0 = *(const float4*)&A[(size_t)(bm + row)      * lda + k0 + slot * 4];
        float4 a1 = *(const float4*)&A[(size_t)(bm + row + 64) * lda + k0 + slot * 4];
        float4 w0 = *(const float4*)&W[(size_t)(bn + row)      * K + k0 + slot * 4];
        float4 w1 = *(const float4*)&W[(size_t)(bn + row + 64) * K + k0 + slot * 4];
        As[slot*4+0][row]    = a0.x; As[slot*4+1][row]    = a0.y;
        As[slot*4+2][row]    = a0.z; As[slot*4+3][row]    = a0.w;
        As[slot*4+0][row+64] = a1.x; As[slot*4+1][row+64] = a1.y;
        As[slot*4+2][row+64] = a1.z; As[slot*4+3][row+64] = a1.w;
        Ws[slot*4+0][row]    = w0.x; Ws[slot*4+1][row]    = w0.y;
        Ws[slot*4+2][row]    = w0.z; Ws[slot*4+3][row]    = w0.w;
        Ws[slot*4+0][row+64] = w1.x; Ws[slot*4+1][row+64] = w1.y;
        Ws[slot*4+2][row+64] = w1.z; Ws[slot*4+3][row+64] = w1.w;
        __syncthreads();

        #pragma unroll
        for (int k = 0; k < 16; k++) {
            float a[8], b[8];
            *(float4*)&a[0] = *(const float4*)&As[k][ty * 8];
            *(float4*)&a[4] = *(const float4*)&As[k][ty * 8 + 4];
            *(float4*)&b[0] = *(const float4*)&Ws[k][tx * 8];
            *(float4*)&b[4] = *(const float4*)&Ws[k][tx * 8 + 4];
            #pragma unroll
            for (int i = 0; i < 8; i++)
                #pragma unroll
                for (int j = 0; j < 8; j++)
                    acc[i][j] = fmaf(a[i], b[j], acc[i][j]);
        }
        __syncthreads();
    }

    #pragma unroll
    for (int i = 0; i < 8; i++) {
        const int m = bm + ty * 8 + i;
        #pragma unroll
        for (int j = 0; j < 8; j++) {
            const int n = bn + tx * 8 + j;
            float v = acc[i][j] + bias[n];
            v = (v > 20.f) ? v : log1pf(__expf(v));
            C[(size_t)m * ldc + n] = f2bf(v);
        }
    }
}

// ---------------- depthwise causal conv(4) + bias + silu, bf16 in/out ----------------
__global__ __launch_bounds__(256)
void conv_silu_kernel(unsigned short* __restrict__ U, const unsigned short* __restrict__ P,
                      const float* __restrict__ cw, const float* __restrict__ cb)
{
    const int idx8 = blockIdx.x * 256 + threadIdx.x;
    const int d0 = (idx8 & 255) * 8;
    const int t  = (idx8 >> 8) & (SEQ - 1);
    const size_t base = (size_t)idx8 * 8;

    float s[8];
    #pragma unroll
    for (int i = 0; i < 8; i++) s[i] = cb[d0 + i];
    #pragma unroll
    for (int k = 0; k < 4; k++) {
        const int tt = t - 3 + k;
        if (tt < 0) continue;
        float v[8];
        unpack8(*(const uint4*)&P[base + (ptrdiff_t)(k - 3) * DINNER], v);
        #pragma unroll
        for (int i = 0; i < 8; i++) s[i] = fmaf(cw[(d0 + i) * 4 + k], v[i], s[i]);
    }
    #pragma unroll
    for (int i = 0; i < 8; i++) s[i] = silu(s[i]);
    *(uint4*)&U[base] = pack8(s);
}

// ---------------- selective scan: 16 lanes/channel, 4 states/lane, 4 ch/wave ----------------
// delta (bf16) read from P16, y (bf16) written over it. u bf16, B/C fp32.
__global__ __launch_bounds__(256)
void scan_kernel(unsigned short* __restrict__ P16, const unsigned short* __restrict__ U16,
                 const float* __restrict__ XDB, const float* __restrict__ A_log)
{
    const int gid  = blockIdx.x * 256 + threadIdx.x;
    const int wave = gid >> 6;            // 0..2047
    const int lane = gid & 63;
    const int sub  = lane & 15;           // lane within channel group
    const int ch   = wave * 4 + (lane >> 4);  // global channel 0..8191
    const int b    = ch >> 11;
    const int d    = ch & (DINNER - 1);
    const int n0   = sub * 4;             // this lane's 4 states

    // A'' = -exp(A_log) * log2(e)  (per state), so dA = exp2(dl * A'')
    float An[4];
    #pragma unroll
    for (int i = 0; i < 4; i++)
        An[i] = -1.44269504f * __expf(A_log[d * DSTATE + n0 + i]);

    float h[4] = {0.f, 0.f, 0.f, 0.f};

    unsigned short*       pp = P16 + (size_t)b * SEQ * DINNER + d;
    const unsigned short* up = U16 + (size_t)b * SEQ * DINNER + d;
    const float*          xp = XDB + (size_t)b * SEQ * XDBW;

    for (int t0 = 0; t0 < SEQ; t0 += 8) {
        float dl[8], uu[8];
        float4 Bt[8], Ct[8];
        #pragma unroll
        for (int j = 0; j < 8; j++) {
            dl[j] = bf2f(pp[(size_t)(t0 + j) * DINNER]);
            uu[j] = bf2f(up[(size_t)(t0 + j) * DINNER]);
            Bt[j] = *(const float4*)&xp[(t0 + j) * XDBW + 64 + n0];
            Ct[j] = *(const float4*)&xp[(t0 + j) * XDBW + 128 + n0];
        }
        float p[8];
        #pragma unroll
        for (int j = 0; j < 8; j++) {
            const float dlu = dl[j] * uu[j];
            h[0] = fmaf(exp2f(dl[j] * An[0]), h[0], dlu * Bt[j].x);
            h[1] = fmaf(exp2f(dl[j] * An[1]), h[1], dlu * Bt[j].y);
            h[2] = fmaf(exp2f(dl[j] * An[2]), h[2], dlu * Bt[j].z);
            h[3] = fmaf(exp2f(dl[j] * An[3]), h[3], dlu * Bt[j].w);
            float q;
            q = h[0] * Ct[j].x;
            q = fmaf(h[1], Ct[j].y, q);
            q = fmaf(h[2], Ct[j].z, q);
            q = fmaf(h[3], Ct[j].w, q);
            p[j] = q;
        }
        // 16-lane reduce (stays within the channel's lane group), 8 t's interleaved
        #pragma unroll
        for (int off = 8; off; off >>= 1)
            #pragma unroll
            for (int j = 0; j < 8; j++) p[j] += __shfl_xor(p[j], off);
        if (sub == 0) {
            #pragma unroll
            for (int j = 0; j < 8; j++) pp[(size_t)(t0 + j) * DINNER] = f2bf(p[j]);
        }
    }
}

// ---------------- gate: G = (y + u*Dsk) * silu(z), bf16, G over Z16 ----------------
__global__ __launch_bounds__(256)
void gate_kernel(unsigned short* __restrict__ Z16, const unsigned short* __restrict__ P16,
                 const unsigned short* __restrict__ U16, const float* __restrict__ Dsk)
{
    const int idx8 = blockIdx.x * 256 + threadIdx.x;
    const int d0 = (idx8 & 255) * 8;
    const size_t base = (size_t)idx8 * 8;
    float y[8], u[8], z[8];
    unpack8(*(const uint4*)&P16[base], y);
    unpack8(*(const uint4*)&U16[base], u);
    unpack8(*(const uint4*)&Z16[base], z);
    float g[8];
    #pragma unroll
    for (int i = 0; i < 8; i++) g[i] = (y[i] + u[i] * Dsk[d0 + i]) * silu(z[i]);
    *(uint4*)&Z16[base] = pack8(g);
}

// ---------------- casts ----------------
__global__ __launch_bounds__(256)
void cast_f2b_kernel(unsigned short* __restrict__ o, const float* __restrict__ in, int n8)
{
    const int i = blockIdx.x * 256 + threadIdx.x;
    if (i >= n8) return;
    float f[8];
    *(float4*)&f[0] = ((const float4*)in)[2 * i];
    *(float4*)&f[4] = ((const float4*)in)[2 * i + 1];
    ((uint4*)o)[i] = pack8(f);
}

__global__ __launch_bounds__(256)
void cast_xp_kernel(unsigned short* __restrict__ o, const float* __restrict__ in)
{
    const int i = blockIdx.x * 256 + threadIdx.x;
    const int k8 = i & 255;
    const int n  = (i >> 8) & 255;
    const int l  = i >> 16;
    float f[8] = {0.f, 0.f, 0.f, 0.f, 0.f, 0.f, 0.f, 0.f};
    if (n < 192) {
        const float* src = in + ((size_t)l * 192 + n) * 2048 + k8 * 8;
        *(float4*)&f[0] = *(const float4*)&src[0];
        *(float4*)&f[4] = *(const float4*)&src[4];
    }
    ((uint4*)o)[i] = pack8(f);
}

// ---------------- layernorm ----------------
__global__ __launch_bounds__(256)
void ln_kernel(float* __restrict__ out, const float* __restrict__ X,
               const float* __restrict__ gam, const float* __restrict__ bet)
{
    const int gid  = blockIdx.x * 256 + threadIdx.x;
    const int wave = gid >> 6;
    const int lane = gid & 63;
    const float* row = X + (size_t)wave * DMODEL;

    float4 v[4];
    float s = 0.f;
    #pragma unroll
    for (int i = 0; i < 4; i++) {
        v[i] = *(const float4*)&row[i * 256 + lane * 4];
        s += v[i].x + v[i].y + v[i].z + v[i].w;
    }
    #pragma unroll
    for (int off = 32; off; off >>= 1) s += __shfl_xor(s, off);
    const float mu = s * (1.f / 1024.f);

    float q = 0.f;
    #pragma unroll
    for (int i = 0; i < 4; i++) {
        float dx = v[i].x - mu; q = fmaf(dx, dx, q);
        dx = v[i].y - mu;       q = fmaf(dx, dx, q);
        dx = v[i].z - mu;       q = fmaf(dx, dx, q);
        dx = v[i].w - mu;       q = fmaf(dx, dx, q);
    }
    #pragma unroll
    for (int off = 32; off; off >>= 1) q += __shfl_xor(q, off);
    const float rstd = rsqrtf(q * (1.f / 1024.f) + 1e-5f);

    #pragma unroll
    for (int i = 0; i < 4; i++) {
        const int col = i * 256 + lane * 4;
        const float4 g = *(const float4*)&gam[col];
        const float4 bb = *(const float4*)&bet[col];
        float4 o;
        o.x = nanfix((v[i].x - mu) * rstd * g.x + bb.x);
        o.y = nanfix((v[i].y - mu) * rstd * g.y + bb.y);
        o.z = nanfix((v[i].z - mu) * rstd * g.z + bb.z);
        o.w = nanfix((v[i].w - mu) * rstd * g.w + bb.w);
        *(float4*)&out[(size_t)wave * DMODEL + col] = o;
    }
}

extern "C" void kernel_launch(void* const* d_in, const int* in_sizes, int n_in,
                              void* d_out, int out_size, void* d_ws, size_t ws_size,
                              hipStream_t stream)
{
    const float* x_in   = (const float*)d_in[0];
    const float* in_w   = (const float*)d_in[2];
    const float* conv_w = (const float*)d_in[3];
    const float* conv_b = (const float*)d_in[4];
    const float* xp_w   = (const float*)d_in[5];
    const float* dtp_w  = (const float*)d_in[6];
    const float* dtp_b  = (const float*)d_in[7];
    const float* A_log  = (const float*)d_in[8];
    const float* D_skip = (const float*)d_in[9];
    const float* out_w  = (const float*)d_in[10];
    const float* gam    = (const float*)d_in[11];
    const float* bet    = (const float*)d_in[12];

    float* Xres = (float*)d_out;

    char* w = (char*)d_ws;
    unsigned short* Win  = (unsigned short*)w;  w += (size_t)NLAYERS * 4096 * 1024 * 2;
    unsigned short* Wout = (unsigned short*)w;  w += (size_t)NLAYERS * 1024 * 2048 * 2;
    unsigned short* Wxp  = (unsigned short*)w;  w += (size_t)NLAYERS * 256 * 2048 * 2;
    unsigned short* Xbf  = (unsigned short*)w;  w += (size_t)MROWS * 1024 * 2;
    unsigned short* P16  = (unsigned short*)w;  w += (size_t)MROWS * 2048 * 2;
    unsigned short* Z16  = (unsigned short*)w;  w += (size_t)MROWS * 2048 * 2;
    unsigned short* U16  = (unsigned short*)w;  w += (size_t)MROWS * 2048 * 2;
    float*          XDB  = (float*)w;

    hipMemcpyAsync(Xres, x_in, (size_t)MROWS * DMODEL * sizeof(float),
                   hipMemcpyDeviceToDevice, stream);

    cast_f2b_kernel<<<8192, 256, 0, stream>>>(Win, in_w, 2097152);
    cast_f2b_kernel<<<4096, 256, 0, stream>>>(Wout, out_w, 1048576);
    cast_xp_kernel<<<1024, 256, 0, stream>>>(Wxp, xp_w);

    for (int l = 0; l < NLAYERS; l++) {
        const unsigned short* winl = Win + (size_t)l * 4096 * 1024;
        const unsigned short* wol  = Wout + (size_t)l * 1024 * 2048;
        const unsigned short* wxl  = Wxp + (size_t)l * 256 * 2048;
        const float* cw  = conv_w + (size_t)l * DINNER * 4;
        const float* cb  = conv_b + (size_t)l * DINNER;
        const float* dtw = dtp_w  + (size_t)l * DINNER * DTRANK;
        const float* dtb = dtp_b  + (size_t)l * DINNER;
        const float* Al  = A_log  + (size_t)l * DINNER * DSTATE;
        const float* Dl  = D_skip + (size_t)l * DINNER;

        cast_f2b_kernel<<<4096, 256, 0, stream>>>(Xbf, Xres, 1048576);
        mgemm_kernel<0><<<dim3(64, 16), 256, 0, stream>>>(P16, Xbf, winl,
                                                          DINNER, DMODEL, DINNER);
        mgemm_kernel<0><<<dim3(64, 16), 256, 0, stream>>>(Z16, Xbf, winl + 2048 * 1024,
                                                          DINNER, DMODEL, DINNER);
        conv_silu_kernel<<<8192, 256, 0, stream>>>(U16, P16, cw, cb);
        mgemm_kernel<1><<<dim3(64, 2), 256, 0, stream>>>(XDB, U16, wxl,
                                                         XDBW, DINNER, XDBW);
        gemm_delta_kernel<<<dim3(64, 16), 256, 0, stream>>>(P16, XDB, dtw, dtb,
                                                            MROWS, DINNER, DTRANK, XDBW, DINNER);
        scan_kernel<<<512, 256, 0, stream>>>(P16, U16, XDB, Al);
        gate_kernel<<<8192, 256, 0, stream>>>(Z16, P16, U16, Dl);
        mgemm_kernel<2><<<dim3(64, 8), 256, 0, stream>>>(Xres, Z16, wol,
                                                         DMODEL, DINNER, DMODEL);
    }

    ln_kernel<<<2048, 256, 0, stream>>>(Xres, Xres, gam, bet);
}

// Round 5
// 3821.314 us; speedup vs baseline: 1.6603x; 1.6603x over previous
//
#include <hip/hip_runtime.h>
#include <math.h>

#define SEQ     2048
#define DMODEL  1024
#define DINNER  2048
#define DSTATE  64
#define DTRANK  64
#define NLAYERS 4
#define XDBW    192
#define MROWS   8192   // 4*SEQ

typedef __attribute__((ext_vector_type(8))) short bf16x8;
typedef __attribute__((ext_vector_type(4))) float f32x4;

__device__ __forceinline__ float nanfix(float x) {
    if (x != x) return 0.f;
    return fminf(fmaxf(x, -3.402823466e38f), 3.402823466e38f);
}
__device__ __forceinline__ float silu(float x) { return x / (1.f + __expf(-x)); }
__device__ __forceinline__ float bf2f(unsigned short u) {
    return __uint_as_float((unsigned int)u << 16);
}
__device__ __forceinline__ unsigned short f2bf(float f) {
    unsigned int u = __float_as_uint(f);
    u += 0x7FFFu + ((u >> 16) & 1u);
    return (unsigned short)(u >> 16);
}
__device__ __forceinline__ void unpack8(uint4 r, float* f) {
    f[0] = __uint_as_float(r.x << 16); f[1] = __uint_as_float(r.x & 0xFFFF0000u);
    f[2] = __uint_as_float(r.y << 16); f[3] = __uint_as_float(r.y & 0xFFFF0000u);
    f[4] = __uint_as_float(r.z << 16); f[5] = __uint_as_float(r.z & 0xFFFF0000u);
    f[6] = __uint_as_float(r.w << 16); f[7] = __uint_as_float(r.w & 0xFFFF0000u);
}
__device__ __forceinline__ uint4 pack8(const float* f) {
    uint4 r;
    r.x = (unsigned int)f2bf(f[0]) | ((unsigned int)f2bf(f[1]) << 16);
    r.y = (unsigned int)f2bf(f[2]) | ((unsigned int)f2bf(f[3]) << 16);
    r.z = (unsigned int)f2bf(f[4]) | ((unsigned int)f2bf(f[5]) << 16);
    r.w = (unsigned int)f2bf(f[6]) | ((unsigned int)f2bf(f[7]) << 16);
    return r;
}

#define GLDS16(g, l) __builtin_amdgcn_global_load_lds( \
    (const __attribute__((address_space(1))) void*)(g), \
    (__attribute__((address_space(3))) void*)(l), 16, 0, 0)

// ---------------- bf16 MFMA GEMM: C[M,N] = A[M,K] * W[N,K]^T ----------------
template<int EPI>
__global__ __launch_bounds__(256)
void mgemm_kernel(void* __restrict__ Cp, const unsigned short* __restrict__ A,
                  const unsigned short* __restrict__ W, int N, int K, int ldc)
{
    __shared__ unsigned short As[128 * 32];
    __shared__ unsigned short Bs[128 * 32];
    const int tid  = threadIdx.x;
    const int lane = tid & 63;
    const int wv   = tid >> 6;
    const int wr   = (wv >> 1) * 64;
    const int wc   = (wv & 1) * 64;
    const int bm   = blockIdx.x * 128;
    const int bn   = blockIdx.y * 128;

    const int fr = lane & 15;
    const int kq = (lane >> 4) * 8;

    const int g_row = wv * 16 + (lane >> 2);
    const int g_col = (lane & 3) * 8;
    const unsigned short* a0 = A + (size_t)(bm + g_row) * K + g_col;
    const unsigned short* a1 = A + (size_t)(bm + 64 + g_row) * K + g_col;
    const unsigned short* b0 = W + (size_t)(bn + g_row) * K + g_col;
    const unsigned short* b1 = W + (size_t)(bn + 64 + g_row) * K + g_col;
    unsigned short* lA0 = &As[wv * 512];
    unsigned short* lA1 = &As[2048 + wv * 512];
    unsigned short* lB0 = &Bs[wv * 512];
    unsigned short* lB1 = &Bs[2048 + wv * 512];

    f32x4 acc[4][4];
    #pragma unroll
    for (int i = 0; i < 4; i++)
        #pragma unroll
        for (int j = 0; j < 4; j++) acc[i][j] = (f32x4){0.f, 0.f, 0.f, 0.f};

    for (int k0 = 0; k0 < K; k0 += 32) {
        GLDS16(a0 + k0, lA0);
        GLDS16(a1 + k0, lA1);
        GLDS16(b0 + k0, lB0);
        GLDS16(b1 + k0, lB1);
        __syncthreads();

        bf16x8 af[4], bfv[4];
        #pragma unroll
        for (int mi = 0; mi < 4; mi++)
            af[mi] = *(const bf16x8*)&As[(wr + mi * 16 + fr) * 32 + kq];
        #pragma unroll
        for (int ni = 0; ni < 4; ni++)
            bfv[ni] = *(const bf16x8*)&Bs[(wc + ni * 16 + fr) * 32 + kq];
        #pragma unroll
        for (int mi = 0; mi < 4; mi++)
            #pragma unroll
            for (int ni = 0; ni < 4; ni++)
                acc[mi][ni] = __builtin_amdgcn_mfma_f32_16x16x32_bf16(
                    af[mi], bfv[ni], acc[mi][ni], 0, 0, 0);
        __syncthreads();
    }

    const int orow = (lane >> 4) * 4;
    #pragma unroll
    for (int mi = 0; mi < 4; mi++) {
        #pragma unroll
        for (int r = 0; r < 4; r++) {
            const int row = bm + wr + mi * 16 + orow + r;
            #pragma unroll
            for (int ni = 0; ni < 4; ni++) {
                const int col = bn + wc + ni * 16 + fr;
                const float v = acc[mi][ni][r];
                if (EPI == 0) {
                    ((unsigned short*)Cp)[(size_t)row * ldc + col] = f2bf(v);
                } else if (EPI == 1) {
                    if (col < N) ((float*)Cp)[(size_t)row * ldc + col] = v;
                } else {
                    float* C = (float*)Cp;
                    const size_t o = (size_t)row * ldc + col;
                    C[o] = nanfix(C[o] + nanfix(v));
                }
            }
        }
    }
}

// ---------------- fp32 vector GEMM (delta projection, K=64), softplus, bf16 out ----------------
__global__ __launch_bounds__(256)
void gemm_delta_kernel(unsigned short* __restrict__ C, const float* __restrict__ A,
                       const float* __restrict__ W, const float* __restrict__ bias,
                       int M, int N, int K, int lda, int ldc)
{
    __shared__ float As[16][128];
    __shared__ float Ws[16][128];
    const int tid  = threadIdx.x;
    const int bm   = blockIdx.x * 128;
    const int bn   = blockIdx.y * 128;
    const int tx   = tid & 15;
    const int ty   = tid >> 4;
    const int slot = tid & 3;
    const int row  = tid >> 2;

    float acc[8][8];
    #pragma unroll
    for (int i = 0; i < 8; i++)
        #pragma unroll
        for (int j = 0; j < 8; j++) acc[i][j] = 0.f;

    for (int k0 = 0; k0 < K; k0 += 16) {
        float4 a0 = *(const float4*)&A[(size_t)(bm + row)      * lda + k0 + slot * 4];
        float4 a1 = *(const float4*)&A[(size_t)(bm + row + 64) * lda + k0 + slot * 4];
        float4 w0 = *(const float4*)&W[(size_t)(bn + row)      * K + k0 + slot * 4];
        float4 w1 = *(const float4*)&W[(size_t)(bn + row + 64) * K + k0 + slot * 4];
        As[slot*4+0][row]    = a0.x; As[slot*4+1][row]    = a0.y;
        As[slot*4+2][row]    = a0.z; As[slot*4+3][row]    = a0.w;
        As[slot*4+0][row+64] = a1.x; As[slot*4+1][row+64] = a1.y;
        As[slot*4+2][row+64] = a1.z; As[slot*4+3][row+64] = a1.w;
        Ws[slot*4+0][row]    = w0.x; Ws[slot*4+1][row]    = w0.y;
        Ws[slot*4+2][row]    = w0.z; Ws[slot*4+3][row]    = w0.w;
        Ws[slot*4+0][row+64] = w1.x; Ws[slot*4+1][row+64] = w1.y;
        Ws[slot*4+2][row+64] = w1.z; Ws[slot*4+3][row+64] = w1.w;
        __syncthreads();

        #pragma unroll
        for (int k = 0; k < 16; k++) {
            float a[8], b[8];
            *(float4*)&a[0] = *(const float4*)&As[k][ty * 8];
            *(float4*)&a[4] = *(const float4*)&As[k][ty * 8 + 4];
            *(float4*)&b[0] = *(const float4*)&Ws[k][tx * 8];
            *(float4*)&b[4] = *(const float4*)&Ws[k][tx * 8 + 4];
            #pragma unroll
            for (int i = 0; i < 8; i++)
                #pragma unroll
                for (int j = 0; j < 8; j++)
                    acc[i][j] = fmaf(a[i], b[j], acc[i][j]);
        }
        __syncthreads();
    }

    #pragma unroll
    for (int i = 0; i < 8; i++) {
        const int m = bm + ty * 8 + i;
        #pragma unroll
        for (int j = 0; j < 8; j++) {
            const int n = bn + tx * 8 + j;
            float v = acc[i][j] + bias[n];
            v = (v > 20.f) ? v : log1pf(__expf(v));
            C[(size_t)m * ldc + n] = f2bf(v);
        }
    }
}

// ---------------- depthwise causal conv(4) + bias + silu, bf16 in/out ----------------
__global__ __launch_bounds__(256)
void conv_silu_kernel(unsigned short* __restrict__ U, const unsigned short* __restrict__ P,
                      const float* __restrict__ cw, const float* __restrict__ cb)
{
    const int idx8 = blockIdx.x * 256 + threadIdx.x;
    const int d0 = (idx8 & 255) * 8;
    const int t  = (idx8 >> 8) & (SEQ - 1);
    const size_t base = (size_t)idx8 * 8;

    float s[8];
    #pragma unroll
    for (int i = 0; i < 8; i++) s[i] = cb[d0 + i];
    #pragma unroll
    for (int k = 0; k < 4; k++) {
        const int tt = t - 3 + k;
        if (tt < 0) continue;
        float v[8];
        unpack8(*(const uint4*)&P[base + (ptrdiff_t)(k - 3) * DINNER], v);
        #pragma unroll
        for (int i = 0; i < 8; i++) s[i] = fmaf(cw[(d0 + i) * 4 + k], v[i], s[i]);
    }
    #pragma unroll
    for (int i = 0; i < 8; i++) s[i] = silu(s[i]);
    *(uint4*)&U[base] = pack8(s);
}

// ---------------- selective scan v3: LDS double-buffered, async-stage split ----------------
// Block: 256 threads / 4 waves / 16 channels (16 lanes per channel, 4 states per lane).
// Phase = 16 timesteps. Stage (global->reg) issued before compute, reg->LDS after.
__global__ __launch_bounds__(256, 2)
void scan_kernel(unsigned short* __restrict__ P16, const unsigned short* __restrict__ U16,
                 const float* __restrict__ XDB, const float* __restrict__ A_log)
{
    __shared__ float sBC[2][16][128];   // per t: B[0:64], C[64:128]  (shared by whole block)
    __shared__ float sDL[2][16][16];    // [t][channel]
    __shared__ float sUU[2][16][16];

    const int tid  = threadIdx.x;
    const int lane = tid & 63;
    const int wv   = tid >> 6;
    const int sub  = lane & 15;                 // lane within channel group
    const int chl  = wv * 4 + (lane >> 4);      // channel within block 0..15
    const int g    = blockIdx.x * 16 + chl;     // global channel
    const int d    = g & (DINNER - 1);
    const int n0   = sub * 4;                   // this lane's 4 states

    // A'' = -exp(A_log)*log2(e): dA = exp2(dl * A'')
    float An[4];
    #pragma unroll
    for (int i = 0; i < 4; i++)
        An[i] = -1.44269504f * __expf(A_log[d * DSTATE + n0 + i]);
    float h[4] = {0.f, 0.f, 0.f, 0.f};

    const int bb = (blockIdx.x * 16) >> 11;               // batch index (same for whole block)
    const int d0 = (blockIdx.x * 16) & (DINNER - 1);      // block's base channel
    unsigned short*       pB = P16 + (size_t)bb * SEQ * DINNER + d0;
    const unsigned short* uB = U16 + (size_t)bb * SEQ * DINNER + d0;
    const float*          xp = XDB + (size_t)bb * SEQ * XDBW;
    unsigned short*       yp = pB + (d - d0);             // this lane's channel column

    // stage-thread mapping
    const int st_t  = tid >> 4;     // 0..15   (delta/u: one (t,ch) per thread)
    const int st_ch = tid & 15;
    const int bt    = tid >> 5;     // 0..7    (BC: two float4 per thread, t rows bt and bt+8)
    const int bc4   = (tid & 31) * 4;

    float4 r0, r1; float rdl, ruu;

    // ---- global -> reg for phase t0 ----
    #define SCAN_GLOAD(t0)  do { \
        r0  = *(const float4*)&xp[(size_t)((t0) + bt) * XDBW + 64 + bc4]; \
        r1  = *(const float4*)&xp[(size_t)((t0) + 8 + bt) * XDBW + 64 + bc4]; \
        rdl = bf2f(pB[(size_t)((t0) + st_t) * DINNER + st_ch]); \
        ruu = bf2f(uB[(size_t)((t0) + st_t) * DINNER + st_ch]); \
    } while (0)
    // ---- reg -> LDS ----
    #define SCAN_SWRITE(buf) do { \
        *(float4*)&sBC[buf][bt][bc4]     = r0; \
        *(float4*)&sBC[buf][bt + 8][bc4] = r1; \
        sDL[buf][st_t][st_ch] = rdl; \
        sUU[buf][st_t][st_ch] = ruu; \
    } while (0)

    SCAN_GLOAD(0);
    SCAN_SWRITE(0);
    __syncthreads();

    for (int k = 0; k < SEQ / 16; k++) {
        const int t0 = k * 16;
        if (k < SEQ / 16 - 1) SCAN_GLOAD(t0 + 16);   // issue early; latency hides under compute

        const int buf = k & 1;
        float p[16];
        #pragma unroll
        for (int t = 0; t < 16; t++) {
            const float dl = sDL[buf][t][chl];
            const float uu = sUU[buf][t][chl];
            const float4 Bv = *(const float4*)&sBC[buf][t][n0];
            const float4 Cv = *(const float4*)&sBC[buf][t][64 + n0];
            const float dlu = dl * uu;
            h[0] = fmaf(exp2f(dl * An[0]), h[0], dlu * Bv.x);
            h[1] = fmaf(exp2f(dl * An[1]), h[1], dlu * Bv.y);
            h[2] = fmaf(exp2f(dl * An[2]), h[2], dlu * Bv.z);
            h[3] = fmaf(exp2f(dl * An[3]), h[3], dlu * Bv.w);
            float q = h[0] * Cv.x;
            q = fmaf(h[1], Cv.y, q);
            q = fmaf(h[2], Cv.z, q);
            q = fmaf(h[3], Cv.w, q);
            p[t] = q;
        }
        // 16-lane reduction, 16 t's interleaved for ILP
        #pragma unroll
        for (int off = 8; off; off >>= 1)
            #pragma unroll
            for (int t = 0; t < 16; t++) p[t] += __shfl_xor(p[t], off);
        if (sub == 0) {
            #pragma unroll
            for (int t = 0; t < 16; t++)
                yp[(size_t)(t0 + t) * DINNER] = f2bf(p[t]);
        }

        if (k < SEQ / 16 - 1) SCAN_SWRITE((k + 1) & 1);  // write late (after compute)
        __syncthreads();
    }
    #undef SCAN_GLOAD
    #undef SCAN_SWRITE
}

// ---------------- gate: G = (y + u*Dsk) * silu(z), bf16, G over Z16 ----------------
__global__ __launch_bounds__(256)
void gate_kernel(unsigned short* __restrict__ Z16, const unsigned short* __restrict__ P16,
                 const unsigned short* __restrict__ U16, const float* __restrict__ Dsk)
{
    const int idx8 = blockIdx.x * 256 + threadIdx.x;
    const int d0 = (idx8 & 255) * 8;
    const size_t base = (size_t)idx8 * 8;
    float y[8], u[8], z[8];
    unpack8(*(const uint4*)&P16[base], y);
    unpack8(*(const uint4*)&U16[base], u);
    unpack8(*(const uint4*)&Z16[base], z);
    float g[8];
    #pragma unroll
    for (int i = 0; i < 8; i++) g[i] = (y[i] + u[i] * Dsk[d0 + i]) * silu(z[i]);
    *(uint4*)&Z16[base] = pack8(g);
}

// ---------------- casts ----------------
__global__ __launch_bounds__(256)
void cast_f2b_kernel(unsigned short* __restrict__ o, const float* __restrict__ in, int n8)
{
    const int i = blockIdx.x * 256 + threadIdx.x;
    if (i >= n8) return;
    float f[8];
    *(float4*)&f[0] = ((const float4*)in)[2 * i];
    *(float4*)&f[4] = ((const float4*)in)[2 * i + 1];
    ((uint4*)o)[i] = pack8(f);
}

__global__ __launch_bounds__(256)
void cast_xp_kernel(unsigned short* __restrict__ o, const float* __restrict__ in)
{
    const int i = blockIdx.x * 256 + threadIdx.x;
    const int k8 = i & 255;
    const int n  = (i >> 8) & 255;
    const int l  = i >> 16;
    float f[8] = {0.f, 0.f, 0.f, 0.f, 0.f, 0.f, 0.f, 0.f};
    if (n < 192) {
        const float* src = in + ((size_t)l * 192 + n) * 2048 + k8 * 8;
        *(float4*)&f[0] = *(const float4*)&src[0];
        *(float4*)&f[4] = *(const float4*)&src[4];
    }
    ((uint4*)o)[i] = pack8(f);
}

// ---------------- layernorm ----------------
__global__ __launch_bounds__(256)
void ln_kernel(float* __restrict__ out, const float* __restrict__ X,
               const float* __restrict__ gam, const float* __restrict__ bet)
{
    const int gid  = blockIdx.x * 256 + threadIdx.x;
    const int wave = gid >> 6;
    const int lane = gid & 63;
    const float* row = X + (size_t)wave * DMODEL;

    float4 v[4];
    float s = 0.f;
    #pragma unroll
    for (int i = 0; i < 4; i++) {
        v[i] = *(const float4*)&row[i * 256 + lane * 4];
        s += v[i].x + v[i].y + v[i].z + v[i].w;
    }
    #pragma unroll
    for (int off = 32; off; off >>= 1) s += __shfl_xor(s, off);
    const float mu = s * (1.f / 1024.f);

    float q = 0.f;
    #pragma unroll
    for (int i = 0; i < 4; i++) {
        float dx = v[i].x - mu; q = fmaf(dx, dx, q);
        dx = v[i].y - mu;       q = fmaf(dx, dx, q);
        dx = v[i].z - mu;       q = fmaf(dx, dx, q);
        dx = v[i].w - mu;       q = fmaf(dx, dx, q);
    }
    #pragma unroll
    for (int off = 32; off; off >>= 1) q += __shfl_xor(q, off);
    const float rstd = rsqrtf(q * (1.f / 1024.f) + 1e-5f);

    #pragma unroll
    for (int i = 0; i < 4; i++) {
        const int col = i * 256 + lane * 4;
        const float4 g = *(const float4*)&gam[col];
        const float4 bb = *(const float4*)&bet[col];
        float4 o;
        o.x = nanfix((v[i].x - mu) * rstd * g.x + bb.x);
        o.y = nanfix((v[i].y - mu) * rstd * g.y + bb.y);
        o.z = nanfix((v[i].z - mu) * rstd * g.z + bb.z);
        o.w = nanfix((v[i].w - mu) * rstd * g.w + bb.w);
        *(float4*)&out[(size_t)wave * DMODEL + col] = o;
    }
}

extern "C" void kernel_launch(void* const* d_in, const int* in_sizes, int n_in,
                              void* d_out, int out_size, void* d_ws, size_t ws_size,
                              hipStream_t stream)
{
    const float* x_in   = (const float*)d_in[0];
    const float* in_w   = (const float*)d_in[2];
    const float* conv_w = (const float*)d_in[3];
    const float* conv_b = (const float*)d_in[4];
    const float* xp_w   = (const float*)d_in[5];
    const float* dtp_w  = (const float*)d_in[6];
    const float* dtp_b  = (const float*)d_in[7];
    const float* A_log  = (const float*)d_in[8];
    const float* D_skip = (const float*)d_in[9];
    const float* out_w  = (const float*)d_in[10];
    const float* gam    = (const float*)d_in[11];
    const float* bet    = (const float*)d_in[12];

    float* Xres = (float*)d_out;

    char* w = (char*)d_ws;
    unsigned short* Win  = (unsigned short*)w;  w += (size_t)NLAYERS * 4096 * 1024 * 2;
    unsigned short* Wout = (unsigned short*)w;  w += (size_t)NLAYERS * 1024 * 2048 * 2;
    unsigned short* Wxp  = (unsigned short*)w;  w += (size_t)NLAYERS * 256 * 2048 * 2;
    unsigned short* Xbf  = (unsigned short*)w;  w += (size_t)MROWS * 1024 * 2;
    unsigned short* P16  = (unsigned short*)w;  w += (size_t)MROWS * 2048 * 2;
    unsigned short* Z16  = (unsigned short*)w;  w += (size_t)MROWS * 2048 * 2;
    unsigned short* U16  = (unsigned short*)w;  w += (size_t)MROWS * 2048 * 2;
    float*          XDB  = (float*)w;

    hipMemcpyAsync(Xres, x_in, (size_t)MROWS * DMODEL * sizeof(float),
                   hipMemcpyDeviceToDevice, stream);

    cast_f2b_kernel<<<8192, 256, 0, stream>>>(Win, in_w, 2097152);
    cast_f2b_kernel<<<4096, 256, 0, stream>>>(Wout, out_w, 1048576);
    cast_xp_kernel<<<1024, 256, 0, stream>>>(Wxp, xp_w);

    for (int l = 0; l < NLAYERS; l++) {
        const unsigned short* winl = Win + (size_t)l * 4096 * 1024;
        const unsigned short* wol  = Wout + (size_t)l * 1024 * 2048;
        const unsigned short* wxl  = Wxp + (size_t)l * 256 * 2048;
        const float* cw  = conv_w + (size_t)l * DINNER * 4;
        const float* cb  = conv_b + (size_t)l * DINNER;
        const float* dtw = dtp_w  + (size_t)l * DINNER * DTRANK;
        const float* dtb = dtp_b  + (size_t)l * DINNER;
        const float* Al  = A_log  + (size_t)l * DINNER * DSTATE;
        const float* Dl  = D_skip + (size_t)l * DINNER;

        cast_f2b_kernel<<<4096, 256, 0, stream>>>(Xbf, Xres, 1048576);
        mgemm_kernel<0><<<dim3(64, 16), 256, 0, stream>>>(P16, Xbf, winl,
                                                          DINNER, DMODEL, DINNER);
        mgemm_kernel<0><<<dim3(64, 16), 256, 0, stream>>>(Z16, Xbf, winl + 2048 * 1024,
                                                          DINNER, DMODEL, DINNER);
        conv_silu_kernel<<<8192, 256, 0, stream>>>(U16, P16, cw, cb);
        mgemm_kernel<1><<<dim3(64, 2), 256, 0, stream>>>(XDB, U16, wxl,
                                                         XDBW, DINNER, XDBW);
        gemm_delta_kernel<<<dim3(64, 16), 256, 0, stream>>>(P16, XDB, dtw, dtb,
                                                            MROWS, DINNER, DTRANK, XDBW, DINNER);
        scan_kernel<<<512, 256, 0, stream>>>(P16, U16, XDB, Al);
        gate_kernel<<<8192, 256, 0, stream>>>(Z16, P16, U16, Dl);
        mgemm_kernel<2><<<dim3(64, 8), 256, 0, stream>>>(Xres, Z16, wol,
                                                         DMODEL, DINNER, DMODEL);
    }

    ln_kernel<<<2048, 256, 0, stream>>>(Xres, Xres, gam, bet);
}

// Round 6
// 3574.533 us; speedup vs baseline: 1.7750x; 1.0690x over previous
//
#include <hip/hip_runtime.h>
#include <math.h>

#define SEQ     2048
#define DMODEL  1024
#define DINNER  2048
#define DSTATE  64
#define DTRANK  64
#define NLAYERS 4
#define XDBW    192
#define MROWS   8192   // 4*SEQ

typedef __attribute__((ext_vector_type(8))) short bf16x8;
typedef __attribute__((ext_vector_type(4))) float f32x4;

__device__ __forceinline__ float nanfix(float x) {
    if (x != x) return 0.f;
    return fminf(fmaxf(x, -3.402823466e38f), 3.402823466e38f);
}
__device__ __forceinline__ float silu(float x) { return x / (1.f + __expf(-x)); }
__device__ __forceinline__ float bf2f(unsigned short u) {
    return __uint_as_float((unsigned int)u << 16);
}
__device__ __forceinline__ unsigned short f2bf(float f) {
    unsigned int u = __float_as_uint(f);
    u += 0x7FFFu + ((u >> 16) & 1u);
    return (unsigned short)(u >> 16);
}
__device__ __forceinline__ void unpack8(uint4 r, float* f) {
    f[0] = __uint_as_float(r.x << 16); f[1] = __uint_as_float(r.x & 0xFFFF0000u);
    f[2] = __uint_as_float(r.y << 16); f[3] = __uint_as_float(r.y & 0xFFFF0000u);
    f[4] = __uint_as_float(r.z << 16); f[5] = __uint_as_float(r.z & 0xFFFF0000u);
    f[6] = __uint_as_float(r.w << 16); f[7] = __uint_as_float(r.w & 0xFFFF0000u);
}
__device__ __forceinline__ uint4 pack8(const float* f) {
    uint4 r;
    r.x = (unsigned int)f2bf(f[0]) | ((unsigned int)f2bf(f[1]) << 16);
    r.y = (unsigned int)f2bf(f[2]) | ((unsigned int)f2bf(f[3]) << 16);
    r.z = (unsigned int)f2bf(f[4]) | ((unsigned int)f2bf(f[5]) << 16);
    r.w = (unsigned int)f2bf(f[6]) | ((unsigned int)f2bf(f[7]) << 16);
    return r;
}

#define GLDS16(g, l) __builtin_amdgcn_global_load_lds( \
    (const __attribute__((address_space(1))) void*)(g), \
    (__attribute__((address_space(3))) void*)(l), 16, 0, 0)

// counted-vmcnt pipeline sync primitives
#define VMCNT8()  asm volatile("s_waitcnt vmcnt(8)" ::: "memory")
#define FULL_BAR() do { \
    asm volatile("" ::: "memory"); \
    __builtin_amdgcn_sched_barrier(0); \
    __builtin_amdgcn_s_barrier(); \
    __builtin_amdgcn_sched_barrier(0); \
    asm volatile("" ::: "memory"); \
} while (0)

// ---------------- bf16 MFMA GEMM, 4-deep counted-vmcnt pipeline ----------------
// C[M,N] = A[M,K] * W[N,K]^T. 128x128 tile, BK=32, 4 LDS buffers (64KB),
// loads for tile t+3 issued during tile t -> vmcnt(8) per tile, raw s_barrier.
// EPI 0: dual bf16 store (col<ldc -> Cp, else Cp2 at col-ldc)   [merged in_proj]
// EPI 1: f32 store, col<N guard                                  [x_proj]
// EPI 2: f32 residual nanfix into Cp + bf16 copy into Cp2        [out_proj + cast fusion]
template<int EPI>
__global__ __launch_bounds__(256)
void mgemm_kernel(void* __restrict__ Cp, void* __restrict__ Cp2,
                  const unsigned short* __restrict__ A,
                  const unsigned short* __restrict__ W, int N, int K, int ldc)
{
    __shared__ unsigned short sh[4][2][4096];   // [buf][A=0/B=1][8KB bytes] = 64KB
    const int tid  = threadIdx.x;
    const int lane = tid & 63;
    const int wv   = tid >> 6;
    const int wr   = (wv >> 1) * 64;
    const int wc   = (wv & 1) * 64;
    const int bm   = blockIdx.x * 128;
    const int bn   = blockIdx.y * 128;

    const int fr  = lane & 15;          // fragment row/col
    const int kq8 = (lane >> 4) * 8;    // k-octet base (elements)

    // staging geometry: [128 rows][32 k] per matrix per buffer; thread covers
    // rows tid>>2 and 64+(tid>>2), cols (tid&3)*8 .. +7
    const int srow = tid >> 2;          // 0..63
    const int scol = (tid & 3) * 8;     // element col within BK

    const int NT = K >> 5;              // K/32 tiles (always >= 32 here)

    f32x4 acc[4][4];
    #pragma unroll
    for (int i = 0; i < 4; i++)
        #pragma unroll
        for (int j = 0; j < 4; j++) acc[i][j] = (f32x4){0.f, 0.f, 0.f, 0.f};

    auto STAGE = [&](int t) {
        const int k0 = t * 32;
        unsigned short* bA = &sh[t & 3][0][0];
        unsigned short* bB = &sh[t & 3][1][0];
        GLDS16(A + (size_t)(bm + srow) * K      + k0 + scol, bA + wv * 512);
        GLDS16(A + (size_t)(bm + 64 + srow) * K + k0 + scol, bA + 2048 + wv * 512);
        GLDS16(W + (size_t)(bn + srow) * K      + k0 + scol, bB + wv * 512);
        GLDS16(W + (size_t)(bn + 64 + srow) * K + k0 + scol, bB + 2048 + wv * 512);
    };

    // prologue: stage tiles 0,1,2 (12 loads); wait for tile 0 (8 may remain)
    STAGE(0); STAGE(1); STAGE(2);
    VMCNT8();
    FULL_BAR();

    for (int t = 0; t < NT; t++) {
        if (t + 3 < NT) STAGE(t + 3);   // writes buf (t+3)&3 == (t-1)&3 (free since end of t-1)

        const unsigned short* bA = &sh[t & 3][0][0];
        const unsigned short* bB = &sh[t & 3][1][0];
        bf16x8 af[4], bv[4];
        #pragma unroll
        for (int mi = 0; mi < 4; mi++)
            af[mi] = *(const bf16x8*)&bA[(wr + mi * 16 + fr) * 32 + kq8];
        #pragma unroll
        for (int ni = 0; ni < 4; ni++)
            bv[ni] = *(const bf16x8*)&bB[(wc + ni * 16 + fr) * 32 + kq8];
        #pragma unroll
        for (int mi = 0; mi < 4; mi++)
            #pragma unroll
            for (int ni = 0; ni < 4; ni++)
                acc[mi][ni] = __builtin_amdgcn_mfma_f32_16x16x32_bf16(
                    af[mi], bv[ni], acc[mi][ni], 0, 0, 0);

        // tile t+1's loads (issued at tile t-2) must be complete before next tile:
        // outstanding allowed = issues from t-1 and t (4+4) = 8
        VMCNT8();
        FULL_BAR();
    }

    const int orow = (lane >> 4) * 4;
    #pragma unroll
    for (int mi = 0; mi < 4; mi++) {
        #pragma unroll
        for (int r = 0; r < 4; r++) {
            const int row = bm + wr + mi * 16 + orow + r;
            #pragma unroll
            for (int ni = 0; ni < 4; ni++) {
                const int col = bn + wc + ni * 16 + fr;
                const float v = acc[mi][ni][r];
                if (EPI == 0) {
                    if (col < ldc)
                        ((unsigned short*)Cp)[(size_t)row * ldc + col] = f2bf(v);
                    else
                        ((unsigned short*)Cp2)[(size_t)row * ldc + col - ldc] = f2bf(v);
                } else if (EPI == 1) {
                    if (col < N) ((float*)Cp)[(size_t)row * ldc + col] = v;
                } else {
                    float* C = (float*)Cp;
                    const size_t o = (size_t)row * ldc + col;
                    const float res = nanfix(C[o] + nanfix(v));
                    C[o] = res;
                    ((unsigned short*)Cp2)[o] = f2bf(res);   // bf16 residual for next layer
                }
            }
        }
    }
}

// ---------------- fp32 vector GEMM (delta projection, K=64), softplus, bf16 out ----------------
__global__ __launch_bounds__(256)
void gemm_delta_kernel(unsigned short* __restrict__ C, const float* __restrict__ A,
                       const float* __restrict__ W, const float* __restrict__ bias,
                       int M, int N, int K, int lda, int ldc)
{
    __shared__ float As[16][128];
    __shared__ float Ws[16][128];
    const int tid  = threadIdx.x;
    const int bm   = blockIdx.x * 128;
    const int bn   = blockIdx.y * 128;
    const int tx   = tid & 15;
    const int ty   = tid >> 4;
    const int slot = tid & 3;
    const int row  = tid >> 2;

    float acc[8][8];
    #pragma unroll
    for (int i = 0; i < 8; i++)
        #pragma unroll
        for (int j = 0; j < 8; j++) acc[i][j] = 0.f;

    for (int k0 = 0; k0 < K; k0 += 16) {
        float4 a0 = *(const float4*)&A[(size_t)(bm + row)      * lda + k0 + slot * 4];
        float4 a1 = *(const float4*)&A[(size_t)(bm + row + 64) * lda + k0 + slot * 4];
        float4 w0 = *(const float4*)&W[(size_t)(bn + row)      * K + k0 + slot * 4];
        float4 w1 = *(const float4*)&W[(size_t)(bn + row + 64) * K + k0 + slot * 4];
        As[slot*4+0][row]    = a0.x; As[slot*4+1][row]    = a0.y;
        As[slot*4+2][row]    = a0.z; As[slot*4+3][row]    = a0.w;
        As[slot*4+0][row+64] = a1.x; As[slot*4+1][row+64] = a1.y;
        As[slot*4+2][row+64] = a1.z; As[slot*4+3][row+64] = a1.w;
        Ws[slot*4+0][row]    = w0.x; Ws[slot*4+1][row]    = w0.y;
        Ws[slot*4+2][row]    = w0.z; Ws[slot*4+3][row]    = w0.w;
        Ws[slot*4+0][row+64] = w1.x; Ws[slot*4+1][row+64] = w1.y;
        Ws[slot*4+2][row+64] = w1.z; Ws[slot*4+3][row+64] = w1.w;
        __syncthreads();

        #pragma unroll
        for (int k = 0; k < 16; k++) {
            float a[8], b[8];
            *(float4*)&a[0] = *(const float4*)&As[k][ty * 8];
            *(float4*)&a[4] = *(const float4*)&As[k][ty * 8 + 4];
            *(float4*)&b[0] = *(const float4*)&Ws[k][tx * 8];
            *(float4*)&b[4] = *(const float4*)&Ws[k][tx * 8 + 4];
            #pragma unroll
            for (int i = 0; i < 8; i++)
                #pragma unroll
                for (int j = 0; j < 8; j++)
                    acc[i][j] = fmaf(a[i], b[j], acc[i][j]);
        }
        __syncthreads();
    }

    #pragma unroll
    for (int i = 0; i < 8; i++) {
        const int m = bm + ty * 8 + i;
        #pragma unroll
        for (int j = 0; j < 8; j++) {
            const int n = bn + tx * 8 + j;
            float v = acc[i][j] + bias[n];
            v = (v > 20.f) ? v : log1pf(__expf(v));
            C[(size_t)m * ldc + n] = f2bf(v);
        }
    }
}

// ---------------- depthwise causal conv(4) + bias + silu, bf16 in/out ----------------
__global__ __launch_bounds__(256)
void conv_silu_kernel(unsigned short* __restrict__ U, const unsigned short* __restrict__ P,
                      const float* __restrict__ cw, const float* __restrict__ cb)
{
    const int idx8 = blockIdx.x * 256 + threadIdx.x;
    const int d0 = (idx8 & 255) * 8;
    const int t  = (idx8 >> 8) & (SEQ - 1);
    const size_t base = (size_t)idx8 * 8;

    float s[8];
    #pragma unroll
    for (int i = 0; i < 8; i++) s[i] = cb[d0 + i];
    #pragma unroll
    for (int k = 0; k < 4; k++) {
        const int tt = t - 3 + k;
        if (tt < 0) continue;
        float v[8];
        unpack8(*(const uint4*)&P[base + (ptrdiff_t)(k - 3) * DINNER], v);
        #pragma unroll
        for (int i = 0; i < 8; i++) s[i] = fmaf(cw[(d0 + i) * 4 + k], v[i], s[i]);
    }
    #pragma unroll
    for (int i = 0; i < 8; i++) s[i] = silu(s[i]);
    *(uint4*)&U[base] = pack8(s);
}

// ---------------- selective scan: LDS double-buffered, async-stage split ----------------
__global__ __launch_bounds__(256, 2)
void scan_kernel(unsigned short* __restrict__ P16, const unsigned short* __restrict__ U16,
                 const float* __restrict__ XDB, const float* __restrict__ A_log)
{
    __shared__ float sBC[2][16][128];
    __shared__ float sDL[2][16][16];
    __shared__ float sUU[2][16][16];

    const int tid  = threadIdx.x;
    const int lane = tid & 63;
    const int wv   = tid >> 6;
    const int sub  = lane & 15;
    const int chl  = wv * 4 + (lane >> 4);
    const int g    = blockIdx.x * 16 + chl;
    const int d    = g & (DINNER - 1);
    const int n0   = sub * 4;

    float An[4];
    #pragma unroll
    for (int i = 0; i < 4; i++)
        An[i] = -1.44269504f * __expf(A_log[d * DSTATE + n0 + i]);
    float h[4] = {0.f, 0.f, 0.f, 0.f};

    const int bb = (blockIdx.x * 16) >> 11;
    const int d0 = (blockIdx.x * 16) & (DINNER - 1);
    unsigned short*       pB = P16 + (size_t)bb * SEQ * DINNER + d0;
    const unsigned short* uB = U16 + (size_t)bb * SEQ * DINNER + d0;
    const float*          xp = XDB + (size_t)bb * SEQ * XDBW;
    unsigned short*       yp = pB + (d - d0);

    const int st_t  = tid >> 4;
    const int st_ch = tid & 15;
    const int bt    = tid >> 5;
    const int bc4   = (tid & 31) * 4;

    float4 r0, r1; float rdl, ruu;

    #define SCAN_GLOAD(t0)  do { \
        r0  = *(const float4*)&xp[(size_t)((t0) + bt) * XDBW + 64 + bc4]; \
        r1  = *(const float4*)&xp[(size_t)((t0) + 8 + bt) * XDBW + 64 + bc4]; \
        rdl = bf2f(pB[(size_t)((t0) + st_t) * DINNER + st_ch]); \
        ruu = bf2f(uB[(size_t)((t0) + st_t) * DINNER + st_ch]); \
    } while (0)
    #define SCAN_SWRITE(buf) do { \
        *(float4*)&sBC[buf][bt][bc4]     = r0; \
        *(float4*)&sBC[buf][bt + 8][bc4] = r1; \
        sDL[buf][st_t][st_ch] = rdl; \
        sUU[buf][st_t][st_ch] = ruu; \
    } while (0)

    SCAN_GLOAD(0);
    SCAN_SWRITE(0);
    __syncthreads();

    for (int k = 0; k < SEQ / 16; k++) {
        const int t0 = k * 16;
        if (k < SEQ / 16 - 1) SCAN_GLOAD(t0 + 16);

        const int buf = k & 1;
        float p[16];
        #pragma unroll
        for (int t = 0; t < 16; t++) {
            const float dl = sDL[buf][t][chl];
            const float uu = sUU[buf][t][chl];
            const float4 Bv = *(const float4*)&sBC[buf][t][n0];
            const float4 Cv = *(const float4*)&sBC[buf][t][64 + n0];
            const float dlu = dl * uu;
            h[0] = fmaf(exp2f(dl * An[0]), h[0], dlu * Bv.x);
            h[1] = fmaf(exp2f(dl * An[1]), h[1], dlu * Bv.y);
            h[2] = fmaf(exp2f(dl * An[2]), h[2], dlu * Bv.z);
            h[3] = fmaf(exp2f(dl * An[3]), h[3], dlu * Bv.w);
            float q = h[0] * Cv.x;
            q = fmaf(h[1], Cv.y, q);
            q = fmaf(h[2], Cv.z, q);
            q = fmaf(h[3], Cv.w, q);
            p[t] = q;
        }
        #pragma unroll
        for (int off = 8; off; off >>= 1)
            #pragma unroll
            for (int t = 0; t < 16; t++) p[t] += __shfl_xor(p[t], off);
        if (sub == 0) {
            #pragma unroll
            for (int t = 0; t < 16; t++)
                yp[(size_t)(t0 + t) * DINNER] = f2bf(p[t]);
        }

        if (k < SEQ / 16 - 1) SCAN_SWRITE((k + 1) & 1);
        __syncthreads();
    }
    #undef SCAN_GLOAD
    #undef SCAN_SWRITE
}

// ---------------- gate: G = (y + u*Dsk) * silu(z), bf16, G over Z16 ----------------
__global__ __launch_bounds__(256)
void gate_kernel(unsigned short* __restrict__ Z16, const unsigned short* __restrict__ P16,
                 const unsigned short* __restrict__ U16, const float* __restrict__ Dsk)
{
    const int idx8 = blockIdx.x * 256 + threadIdx.x;
    const int d0 = (idx8 & 255) * 8;
    const size_t base = (size_t)idx8 * 8;
    float y[8], u[8], z[8];
    unpack8(*(const uint4*)&P16[base], y);
    unpack8(*(const uint4*)&U16[base], u);
    unpack8(*(const uint4*)&Z16[base], z);
    float g[8];
    #pragma unroll
    for (int i = 0; i < 8; i++) g[i] = (y[i] + u[i] * Dsk[d0 + i]) * silu(z[i]);
    *(uint4*)&Z16[base] = pack8(g);
}

// ---------------- casts ----------------
__global__ __launch_bounds__(256)
void cast_f2b_kernel(unsigned short* __restrict__ o, const float* __restrict__ in, int n8)
{
    const int i = blockIdx.x * 256 + threadIdx.x;
    if (i >= n8) return;
    float f[8];
    *(float4*)&f[0] = ((const float4*)in)[2 * i];
    *(float4*)&f[4] = ((const float4*)in)[2 * i + 1];
    ((uint4*)o)[i] = pack8(f);
}

__global__ __launch_bounds__(256)
void cast_xp_kernel(unsigned short* __restrict__ o, const float* __restrict__ in)
{
    const int i = blockIdx.x * 256 + threadIdx.x;
    const int k8 = i & 255;
    const int n  = (i >> 8) & 255;
    const int l  = i >> 16;
    float f[8] = {0.f, 0.f, 0.f, 0.f, 0.f, 0.f, 0.f, 0.f};
    if (n < 192) {
        const float* src = in + ((size_t)l * 192 + n) * 2048 + k8 * 8;
        *(float4*)&f[0] = *(const float4*)&src[0];
        *(float4*)&f[4] = *(const float4*)&src[4];
    }
    ((uint4*)o)[i] = pack8(f);
}

// ---------------- layernorm ----------------
__global__ __launch_bounds__(256)
void ln_kernel(float* __restrict__ out, const float* __restrict__ X,
               const float* __restrict__ gam, const float* __restrict__ bet)
{
    const int gid  = blockIdx.x * 256 + threadIdx.x;
    const int wave = gid >> 6;
    const int lane = gid & 63;
    const float* row = X + (size_t)wave * DMODEL;

    float4 v[4];
    float s = 0.f;
    #pragma unroll
    for (int i = 0; i < 4; i++) {
        v[i] = *(const float4*)&row[i * 256 + lane * 4];
        s += v[i].x + v[i].y + v[i].z + v[i].w;
    }
    #pragma unroll
    for (int off = 32; off; off >>= 1) s += __shfl_xor(s, off);
    const float mu = s * (1.f / 1024.f);

    float q = 0.f;
    #pragma unroll
    for (int i = 0; i < 4; i++) {
        float dx = v[i].x - mu; q = fmaf(dx, dx, q);
        dx = v[i].y - mu;       q = fmaf(dx, dx, q);
        dx = v[i].z - mu;       q = fmaf(dx, dx, q);
        dx = v[i].w - mu;       q = fmaf(dx, dx, q);
    }
    #pragma unroll
    for (int off = 32; off; off >>= 1) q += __shfl_xor(q, off);
    const float rstd = rsqrtf(q * (1.f / 1024.f) + 1e-5f);

    #pragma unroll
    for (int i = 0; i < 4; i++) {
        const int col = i * 256 + lane * 4;
        const float4 g = *(const float4*)&gam[col];
        const float4 bb = *(const float4*)&bet[col];
        float4 o;
        o.x = nanfix((v[i].x - mu) * rstd * g.x + bb.x);
        o.y = nanfix((v[i].y - mu) * rstd * g.y + bb.y);
        o.z = nanfix((v[i].z - mu) * rstd * g.z + bb.z);
        o.w = nanfix((v[i].w - mu) * rstd * g.w + bb.w);
        *(float4*)&out[(size_t)wave * DMODEL + col] = o;
    }
}

extern "C" void kernel_launch(void* const* d_in, const int* in_sizes, int n_in,
                              void* d_out, int out_size, void* d_ws, size_t ws_size,
                              hipStream_t stream)
{
    const float* x_in   = (const float*)d_in[0];
    const float* in_w   = (const float*)d_in[2];
    const float* conv_w = (const float*)d_in[3];
    const float* conv_b = (const float*)d_in[4];
    const float* xp_w   = (const float*)d_in[5];
    const float* dtp_w  = (const float*)d_in[6];
    const float* dtp_b  = (const float*)d_in[7];
    const float* A_log  = (const float*)d_in[8];
    const float* D_skip = (const float*)d_in[9];
    const float* out_w  = (const float*)d_in[10];
    const float* gam    = (const float*)d_in[11];
    const float* bet    = (const float*)d_in[12];

    float* Xres = (float*)d_out;

    char* w = (char*)d_ws;
    unsigned short* Win  = (unsigned short*)w;  w += (size_t)NLAYERS * 4096 * 1024 * 2;
    unsigned short* Wout = (unsigned short*)w;  w += (size_t)NLAYERS * 1024 * 2048 * 2;
    unsigned short* Wxp  = (unsigned short*)w;  w += (size_t)NLAYERS * 256 * 2048 * 2;
    unsigned short* Xbf  = (unsigned short*)w;  w += (size_t)MROWS * 1024 * 2;
    unsigned short* P16  = (unsigned short*)w;  w += (size_t)MROWS * 2048 * 2;
    unsigned short* Z16  = (unsigned short*)w;  w += (size_t)MROWS * 2048 * 2;
    unsigned short* U16  = (unsigned short*)w;  w += (size_t)MROWS * 2048 * 2;
    float*          XDB  = (float*)w;

    hipMemcpyAsync(Xres, x_in, (size_t)MROWS * DMODEL * sizeof(float),
                   hipMemcpyDeviceToDevice, stream);

    cast_f2b_kernel<<<8192, 256, 0, stream>>>(Win, in_w, 2097152);
    cast_f2b_kernel<<<4096, 256, 0, stream>>>(Wout, out_w, 1048576);
    cast_xp_kernel<<<1024, 256, 0, stream>>>(Wxp, xp_w);
    // initial bf16 residual (layers 1-3 get it fused from mgemm<2> epilogue)
    cast_f2b_kernel<<<4096, 256, 0, stream>>>(Xbf, Xres, 1048576);

    for (int l = 0; l < NLAYERS; l++) {
        const unsigned short* winl = Win + (size_t)l * 4096 * 1024;
        const unsigned short* wol  = Wout + (size_t)l * 1024 * 2048;
        const unsigned short* wxl  = Wxp + (size_t)l * 256 * 2048;
        const float* cw  = conv_w + (size_t)l * DINNER * 4;
        const float* cb  = conv_b + (size_t)l * DINNER;
        const float* dtw = dtp_w  + (size_t)l * DINNER * DTRANK;
        const float* dtb = dtp_b  + (size_t)l * DINNER;
        const float* Al  = A_log  + (size_t)l * DINNER * DSTATE;
        const float* Dl  = D_skip + (size_t)l * DINNER;

        // merged in_proj: cols 0..2047 -> P16 (u_pre), 2048..4095 -> Z16 (z)
        mgemm_kernel<0><<<dim3(64, 32), 256, 0, stream>>>(P16, Z16, Xbf, winl,
                                                          4096, DMODEL, DINNER);
        conv_silu_kernel<<<8192, 256, 0, stream>>>(U16, P16, cw, cb);
        mgemm_kernel<1><<<dim3(64, 2), 256, 0, stream>>>(XDB, nullptr, U16, wxl,
                                                         XDBW, DINNER, XDBW);
        gemm_delta_kernel<<<dim3(64, 16), 256, 0, stream>>>(P16, XDB, dtw, dtb,
                                                            MROWS, DINNER, DTRANK, XDBW, DINNER);
        scan_kernel<<<512, 256, 0, stream>>>(P16, U16, XDB, Al);
        gate_kernel<<<8192, 256, 0, stream>>>(Z16, P16, U16, Dl);
        // residual accumulate + fused bf16 cast for next layer
        mgemm_kernel<2><<<dim3(64, 8), 256, 0, stream>>>(Xres, Xbf, Z16, wol,
                                                         DMODEL, DINNER, DMODEL);
    }

    ln_kernel<<<2048, 256, 0, stream>>>(Xres, Xres, gam, bet);
}

// Round 7
// 2559.463 us; speedup vs baseline: 2.4789x; 1.3966x over previous
//
#include <hip/hip_runtime.h>
#include <math.h>

#define SEQ     2048
#define DMODEL  1024
#define DINNER  2048
#define DSTATE  64
#define DTRANK  64
#define NLAYERS 4
#define XDBW    192
#define MROWS   8192   // 4*SEQ

typedef __attribute__((ext_vector_type(8))) short bf16x8;
typedef __attribute__((ext_vector_type(4))) float f32x4;

#if defined(__has_builtin)
#  if __has_builtin(__builtin_amdgcn_exp2f)
#    define EXP2(x) __builtin_amdgcn_exp2f(x)
#  else
#    define EXP2(x) exp2f(x)
#  endif
#else
#  define EXP2(x) exp2f(x)
#endif

__device__ __forceinline__ float nanfix(float x) {
    if (x != x) return 0.f;
    return fminf(fmaxf(x, -3.402823466e38f), 3.402823466e38f);
}
__device__ __forceinline__ float silu(float x) { return x / (1.f + __expf(-x)); }
__device__ __forceinline__ float bf2f(unsigned short u) {
    return __uint_as_float((unsigned int)u << 16);
}
__device__ __forceinline__ unsigned short f2bf(float f) {
    unsigned int u = __float_as_uint(f);
    u += 0x7FFFu + ((u >> 16) & 1u);
    return (unsigned short)(u >> 16);
}
__device__ __forceinline__ void unpack8(uint4 r, float* f) {
    f[0] = __uint_as_float(r.x << 16); f[1] = __uint_as_float(r.x & 0xFFFF0000u);
    f[2] = __uint_as_float(r.y << 16); f[3] = __uint_as_float(r.y & 0xFFFF0000u);
    f[4] = __uint_as_float(r.z << 16); f[5] = __uint_as_float(r.z & 0xFFFF0000u);
    f[6] = __uint_as_float(r.w << 16); f[7] = __uint_as_float(r.w & 0xFFFF0000u);
}
__device__ __forceinline__ uint4 pack8(const float* f) {
    uint4 r;
    r.x = (unsigned int)f2bf(f[0]) | ((unsigned int)f2bf(f[1]) << 16);
    r.y = (unsigned int)f2bf(f[2]) | ((unsigned int)f2bf(f[3]) << 16);
    r.z = (unsigned int)f2bf(f[4]) | ((unsigned int)f2bf(f[5]) << 16);
    r.w = (unsigned int)f2bf(f[6]) | ((unsigned int)f2bf(f[7]) << 16);
    return r;
}

#define GLDS16(g, l) __builtin_amdgcn_global_load_lds( \
    (const __attribute__((address_space(1))) void*)(g), \
    (__attribute__((address_space(3))) void*)(l), 16, 0, 0)

#define VMCNT8()  asm volatile("s_waitcnt vmcnt(8)" ::: "memory")
#define FULL_BAR() do { \
    asm volatile("" ::: "memory"); \
    __builtin_amdgcn_sched_barrier(0); \
    __builtin_amdgcn_s_barrier(); \
    __builtin_amdgcn_sched_barrier(0); \
    asm volatile("" ::: "memory"); \
} while (0)

// ---------------- bf16 MFMA GEMM, 4-deep counted-vmcnt pipeline ----------------
template<int EPI>
__global__ __launch_bounds__(256)
void mgemm_kernel(void* __restrict__ Cp, void* __restrict__ Cp2,
                  const unsigned short* __restrict__ A,
                  const unsigned short* __restrict__ W, int N, int K, int ldc)
{
    __shared__ unsigned short sh[4][2][4096];
    const int tid  = threadIdx.x;
    const int lane = tid & 63;
    const int wv   = tid >> 6;
    const int wr   = (wv >> 1) * 64;
    const int wc   = (wv & 1) * 64;
    const int bm   = blockIdx.x * 128;
    const int bn   = blockIdx.y * 128;

    const int fr  = lane & 15;
    const int kq8 = (lane >> 4) * 8;
    const int srow = tid >> 2;
    const int scol = (tid & 3) * 8;
    const int NT = K >> 5;

    f32x4 acc[4][4];
    #pragma unroll
    for (int i = 0; i < 4; i++)
        #pragma unroll
        for (int j = 0; j < 4; j++) acc[i][j] = (f32x4){0.f, 0.f, 0.f, 0.f};

    auto STAGE = [&](int t) {
        const int k0 = t * 32;
        unsigned short* bA = &sh[t & 3][0][0];
        unsigned short* bB = &sh[t & 3][1][0];
        GLDS16(A + (size_t)(bm + srow) * K      + k0 + scol, bA + wv * 512);
        GLDS16(A + (size_t)(bm + 64 + srow) * K + k0 + scol, bA + 2048 + wv * 512);
        GLDS16(W + (size_t)(bn + srow) * K      + k0 + scol, bB + wv * 512);
        GLDS16(W + (size_t)(bn + 64 + srow) * K + k0 + scol, bB + 2048 + wv * 512);
    };

    STAGE(0); STAGE(1); STAGE(2);
    VMCNT8();
    FULL_BAR();

    for (int t = 0; t < NT; t++) {
        if (t + 3 < NT) STAGE(t + 3);

        const unsigned short* bA = &sh[t & 3][0][0];
        const unsigned short* bB = &sh[t & 3][1][0];
        bf16x8 af[4], bv[4];
        #pragma unroll
        for (int mi = 0; mi < 4; mi++)
            af[mi] = *(const bf16x8*)&bA[(wr + mi * 16 + fr) * 32 + kq8];
        #pragma unroll
        for (int ni = 0; ni < 4; ni++)
            bv[ni] = *(const bf16x8*)&bB[(wc + ni * 16 + fr) * 32 + kq8];
        #pragma unroll
        for (int mi = 0; mi < 4; mi++)
            #pragma unroll
            for (int ni = 0; ni < 4; ni++)
                acc[mi][ni] = __builtin_amdgcn_mfma_f32_16x16x32_bf16(
                    af[mi], bv[ni], acc[mi][ni], 0, 0, 0);

        VMCNT8();
        FULL_BAR();
    }

    const int orow = (lane >> 4) * 4;
    #pragma unroll
    for (int mi = 0; mi < 4; mi++) {
        #pragma unroll
        for (int r = 0; r < 4; r++) {
            const int row = bm + wr + mi * 16 + orow + r;
            #pragma unroll
            for (int ni = 0; ni < 4; ni++) {
                const int col = bn + wc + ni * 16 + fr;
                const float v = acc[mi][ni][r];
                if (EPI == 0) {
                    if (col < ldc)
                        ((unsigned short*)Cp)[(size_t)row * ldc + col] = f2bf(v);
                    else
                        ((unsigned short*)Cp2)[(size_t)row * ldc + col - ldc] = f2bf(v);
                } else if (EPI == 1) {
                    if (col < N) ((float*)Cp)[(size_t)row * ldc + col] = v;
                } else {
                    float* C = (float*)Cp;
                    const size_t o = (size_t)row * ldc + col;
                    const float res = nanfix(C[o] + nanfix(v));
                    C[o] = res;
                    ((unsigned short*)Cp2)[o] = f2bf(res);
                }
            }
        }
    }
}

// ---------------- fp32 vector GEMM (delta projection, K=64), softplus, bf16 out ----------------
__global__ __launch_bounds__(256)
void gemm_delta_kernel(unsigned short* __restrict__ C, const float* __restrict__ A,
                       const float* __restrict__ W, const float* __restrict__ bias,
                       int M, int N, int K, int lda, int ldc)
{
    __shared__ float As[16][128];
    __shared__ float Ws[16][128];
    const int tid  = threadIdx.x;
    const int bm   = blockIdx.x * 128;
    const int bn   = blockIdx.y * 128;
    const int tx   = tid & 15;
    const int ty   = tid >> 4;
    const int slot = tid & 3;
    const int row  = tid >> 2;

    float acc[8][8];
    #pragma unroll
    for (int i = 0; i < 8; i++)
        #pragma unroll
        for (int j = 0; j < 8; j++) acc[i][j] = 0.f;

    for (int k0 = 0; k0 < K; k0 += 16) {
        float4 a0 = *(const float4*)&A[(size_t)(bm + row)      * lda + k0 + slot * 4];
        float4 a1 = *(const float4*)&A[(size_t)(bm + row + 64) * lda + k0 + slot * 4];
        float4 w0 = *(const float4*)&W[(size_t)(bn + row)      * K + k0 + slot * 4];
        float4 w1 = *(const float4*)&W[(size_t)(bn + row + 64) * K + k0 + slot * 4];
        As[slot*4+0][row]    = a0.x; As[slot*4+1][row]    = a0.y;
        As[slot*4+2][row]    = a0.z; As[slot*4+3][row]    = a0.w;
        As[slot*4+0][row+64] = a1.x; As[slot*4+1][row+64] = a1.y;
        As[slot*4+2][row+64] = a1.z; As[slot*4+3][row+64] = a1.w;
        Ws[slot*4+0][row]    = w0.x; Ws[slot*4+1][row]    = w0.y;
        Ws[slot*4+2][row]    = w0.z; Ws[slot*4+3][row]    = w0.w;
        Ws[slot*4+0][row+64] = w1.x; Ws[slot*4+1][row+64] = w1.y;
        Ws[slot*4+2][row+64] = w1.z; Ws[slot*4+3][row+64] = w1.w;
        __syncthreads();

        #pragma unroll
        for (int k = 0; k < 16; k++) {
            float a[8], b[8];
            *(float4*)&a[0] = *(const float4*)&As[k][ty * 8];
            *(float4*)&a[4] = *(const float4*)&As[k][ty * 8 + 4];
            *(float4*)&b[0] = *(const float4*)&Ws[k][tx * 8];
            *(float4*)&b[4] = *(const float4*)&Ws[k][tx * 8 + 4];
            #pragma unroll
            for (int i = 0; i < 8; i++)
                #pragma unroll
                for (int j = 0; j < 8; j++)
                    acc[i][j] = fmaf(a[i], b[j], acc[i][j]);
        }
        __syncthreads();
    }

    #pragma unroll
    for (int i = 0; i < 8; i++) {
        const int m = bm + ty * 8 + i;
        #pragma unroll
        for (int j = 0; j < 8; j++) {
            const int n = bn + tx * 8 + j;
            float v = acc[i][j] + bias[n];
            v = (v > 20.f) ? v : log1pf(__expf(v));
            C[(size_t)m * ldc + n] = f2bf(v);
        }
    }
}

// ---------------- depthwise causal conv(4) + bias + silu, bf16 in/out ----------------
__global__ __launch_bounds__(256)
void conv_silu_kernel(unsigned short* __restrict__ U, const unsigned short* __restrict__ P,
                      const float* __restrict__ cw, const float* __restrict__ cb)
{
    const int idx8 = blockIdx.x * 256 + threadIdx.x;
    const int d0 = (idx8 & 255) * 8;
    const int t  = (idx8 >> 8) & (SEQ - 1);
    const size_t base = (size_t)idx8 * 8;

    float s[8];
    #pragma unroll
    for (int i = 0; i < 8; i++) s[i] = cb[d0 + i];
    #pragma unroll
    for (int k = 0; k < 4; k++) {
        const int tt = t - 3 + k;
        if (tt < 0) continue;
        float v[8];
        unpack8(*(const uint4*)&P[base + (ptrdiff_t)(k - 3) * DINNER], v);
        #pragma unroll
        for (int i = 0; i < 8; i++) s[i] = fmaf(cw[(d0 + i) * 4 + k], v[i], s[i]);
    }
    #pragma unroll
    for (int i = 0; i < 8; i++) s[i] = silu(s[i]);
    *(uint4*)&U[base] = pack8(s);
}

// ---------------- selective scan v4: lane = channel, states in registers ----------------
// Block: 256 threads = 16 channels x 16 reps, each rep owns 4 states (h in VGPRs).
// No shuffle reduce; per-phase (16 t) LDS partial-sum reduction. T14 stage split.
// delta (bf16) read from P16, y (bf16) written over it.
__global__ __launch_bounds__(256)
void scan_kernel(unsigned short* __restrict__ P16, const unsigned short* __restrict__ U16,
                 const float* __restrict__ XDB, const float* __restrict__ A_log)
{
    __shared__ float sB [2][16][128];        // [buf][t][B 0:64 | C 64:128]  16 KB
    __shared__ float sDL[2][16][16];         // [buf][t][ch]                  2 KB
    __shared__ float sUU[2][16][16];         //                               2 KB
    __shared__ float sQ [2][16 * 260];       // [buf][rep*260 + t*16 + ch]   33 KB

    const int tid = threadIdx.x;
    const int ch  = tid & 15;                // channel within block
    const int rep = tid >> 4;                // 0..15, states rep*4..rep*4+3
    const int n0  = rep * 4;

    const int ch0  = blockIdx.x * 16;        // block's base channel (global)
    const int b    = ch0 >> 11;              // batch
    const int dloc = (ch0 & (DINNER - 1)) + ch;

    // A' = -exp(A_log)*log2(e) for this lane's 4 states
    float An[4];
    {
        const float4 a = *(const float4*)&A_log[dloc * DSTATE + n0];
        An[0] = -1.44269504f * __expf(a.x);
        An[1] = -1.44269504f * __expf(a.y);
        An[2] = -1.44269504f * __expf(a.z);
        An[3] = -1.44269504f * __expf(a.w);
    }
    float h[4] = {0.f, 0.f, 0.f, 0.f};

    unsigned short*       pB = P16 + (size_t)b * SEQ * DINNER + (ch0 & (DINNER - 1));
    const unsigned short* uB = U16 + (size_t)b * SEQ * DINNER + (ch0 & (DINNER - 1));
    const float*          xp = XDB + (size_t)b * SEQ * XDBW;

    // staging thread mapping
    const int st_t = tid >> 4;               // 0..15 (t within phase)
    const int st_c = tid & 15;               // channel (dl/uu) or float8-slot (BC)

    unsigned short rdl, ruu; float4 rb0, rb1;

    #define SC_GLOAD(t0) do { \
        rdl = pB[(size_t)((t0) + st_t) * DINNER + st_c]; \
        ruu = uB[(size_t)((t0) + st_t) * DINNER + st_c]; \
        rb0 = *(const float4*)&xp[(size_t)((t0) + st_t) * XDBW + 64 + st_c * 8]; \
        rb1 = *(const float4*)&xp[(size_t)((t0) + st_t) * XDBW + 68 + st_c * 8]; \
    } while (0)
    #define SC_SWRITE(bf) do { \
        sDL[bf][st_t][st_c] = bf2f(rdl); \
        sUU[bf][st_t][st_c] = bf2f(ruu); \
        *(float4*)&sB[bf][st_t][st_c * 8]     = rb0; \
        *(float4*)&sB[bf][st_t][st_c * 8 + 4] = rb1; \
    } while (0)
    // reduce phase j: sum 16 rep-partials for each (t,ch), write y
    #define SC_REDUCE(j) do { \
        const int rb_ = (j) & 1; \
        float s_ = 0.f; \
        _Pragma("unroll") \
        for (int r_ = 0; r_ < 16; r_++) s_ += sQ[rb_][r_ * 260 + st_t * 16 + st_c]; \
        pB[(size_t)((j) * 16 + st_t) * DINNER + st_c] = f2bf(s_); \
    } while (0)

    SC_GLOAD(0);
    SC_SWRITE(0);
    __syncthreads();

    const int NP = SEQ / 16;   // 128 phases
    for (int k = 0; k < NP; k++) {
        if (k + 1 < NP) SC_GLOAD((k + 1) * 16);   // issue early (T14)
        if (k > 0)      SC_REDUCE(k - 1);          // consume prev phase partials

        const int bf = k & 1;
        float qp[16];
        #pragma unroll
        for (int t = 0; t < 16; t++) {
            const float dl  = sDL[bf][t][ch];
            const float dlu = dl * sUU[bf][t][ch];
            const float4 Bv = *(const float4*)&sB[bf][t][n0];
            const float4 Cv = *(const float4*)&sB[bf][t][64 + n0];
            h[0] = fmaf(EXP2(dl * An[0]), h[0], dlu * Bv.x);
            h[1] = fmaf(EXP2(dl * An[1]), h[1], dlu * Bv.y);
            h[2] = fmaf(EXP2(dl * An[2]), h[2], dlu * Bv.z);
            h[3] = fmaf(EXP2(dl * An[3]), h[3], dlu * Bv.w);
            float q = h[0] * Cv.x;
            q = fmaf(h[1], Cv.y, q);
            q = fmaf(h[2], Cv.z, q);
            q = fmaf(h[3], Cv.w, q);
            qp[t] = q;
        }
        #pragma unroll
        for (int t = 0; t < 16; t++)
            sQ[bf][rep * 260 + t * 16 + ch] = qp[t];

        if (k + 1 < NP) SC_SWRITE((k + 1) & 1);    // write late (T14)
        __syncthreads();
    }
    SC_REDUCE(NP - 1);

    #undef SC_GLOAD
    #undef SC_SWRITE
    #undef SC_REDUCE
}

// ---------------- gate: G = (y + u*Dsk) * silu(z), bf16, G over Z16 ----------------
__global__ __launch_bounds__(256)
void gate_kernel(unsigned short* __restrict__ Z16, const unsigned short* __restrict__ P16,
                 const unsigned short* __restrict__ U16, const float* __restrict__ Dsk)
{
    const int idx8 = blockIdx.x * 256 + threadIdx.x;
    const int d0 = (idx8 & 255) * 8;
    const size_t base = (size_t)idx8 * 8;
    float y[8], u[8], z[8];
    unpack8(*(const uint4*)&P16[base], y);
    unpack8(*(const uint4*)&U16[base], u);
    unpack8(*(const uint4*)&Z16[base], z);
    float g[8];
    #pragma unroll
    for (int i = 0; i < 8; i++) g[i] = (y[i] + u[i] * Dsk[d0 + i]) * silu(z[i]);
    *(uint4*)&Z16[base] = pack8(g);
}

// ---------------- casts ----------------
__global__ __launch_bounds__(256)
void cast_f2b_kernel(unsigned short* __restrict__ o, const float* __restrict__ in, int n8)
{
    const int i = blockIdx.x * 256 + threadIdx.x;
    if (i >= n8) return;
    float f[8];
    *(float4*)&f[0] = ((const float4*)in)[2 * i];
    *(float4*)&f[4] = ((const float4*)in)[2 * i + 1];
    ((uint4*)o)[i] = pack8(f);
}

__global__ __launch_bounds__(256)
void cast_xp_kernel(unsigned short* __restrict__ o, const float* __restrict__ in)
{
    const int i = blockIdx.x * 256 + threadIdx.x;
    const int k8 = i & 255;
    const int n  = (i >> 8) & 255;
    const int l  = i >> 16;
    float f[8] = {0.f, 0.f, 0.f, 0.f, 0.f, 0.f, 0.f, 0.f};
    if (n < 192) {
        const float* src = in + ((size_t)l * 192 + n) * 2048 + k8 * 8;
        *(float4*)&f[0] = *(const float4*)&src[0];
        *(float4*)&f[4] = *(const float4*)&src[4];
    }
    ((uint4*)o)[i] = pack8(f);
}

// ---------------- layernorm ----------------
__global__ __launch_bounds__(256)
void ln_kernel(float* __restrict__ out, const float* __restrict__ X,
               const float* __restrict__ gam, const float* __restrict__ bet)
{
    const int gid  = blockIdx.x * 256 + threadIdx.x;
    const int wave = gid >> 6;
    const int lane = gid & 63;
    const float* row = X + (size_t)wave * DMODEL;

    float4 v[4];
    float s = 0.f;
    #pragma unroll
    for (int i = 0; i < 4; i++) {
        v[i] = *(const float4*)&row[i * 256 + lane * 4];
        s += v[i].x + v[i].y + v[i].z + v[i].w;
    }
    #pragma unroll
    for (int off = 32; off; off >>= 1) s += __shfl_xor(s, off);
    const float mu = s * (1.f / 1024.f);

    float q = 0.f;
    #pragma unroll
    for (int i = 0; i < 4; i++) {
        float dx = v[i].x - mu; q = fmaf(dx, dx, q);
        dx = v[i].y - mu;       q = fmaf(dx, dx, q);
        dx = v[i].z - mu;       q = fmaf(dx, dx, q);
        dx = v[i].w - mu;       q = fmaf(dx, dx, q);
    }
    #pragma unroll
    for (int off = 32; off; off >>= 1) q += __shfl_xor(q, off);
    const float rstd = rsqrtf(q * (1.f / 1024.f) + 1e-5f);

    #pragma unroll
    for (int i = 0; i < 4; i++) {
        const int col = i * 256 + lane * 4;
        const float4 g = *(const float4*)&gam[col];
        const float4 bb = *(const float4*)&bet[col];
        float4 o;
        o.x = nanfix((v[i].x - mu) * rstd * g.x + bb.x);
        o.y = nanfix((v[i].y - mu) * rstd * g.y + bb.y);
        o.z = nanfix((v[i].z - mu) * rstd * g.z + bb.z);
        o.w = nanfix((v[i].w - mu) * rstd * g.w + bb.w);
        *(float4*)&out[(size_t)wave * DMODEL + col] = o;
    }
}

extern "C" void kernel_launch(void* const* d_in, const int* in_sizes, int n_in,
                              void* d_out, int out_size, void* d_ws, size_t ws_size,
                              hipStream_t stream)
{
    const float* x_in   = (const float*)d_in[0];
    const float* in_w   = (const float*)d_in[2];
    const float* conv_w = (const float*)d_in[3];
    const float* conv_b = (const float*)d_in[4];
    const float* xp_w   = (const float*)d_in[5];
    const float* dtp_w  = (const float*)d_in[6];
    const float* dtp_b  = (const float*)d_in[7];
    const float* A_log  = (const float*)d_in[8];
    const float* D_skip = (const float*)d_in[9];
    const float* out_w  = (const float*)d_in[10];
    const float* gam    = (const float*)d_in[11];
    const float* bet    = (const float*)d_in[12];

    float* Xres = (float*)d_out;

    char* w = (char*)d_ws;
    unsigned short* Win  = (unsigned short*)w;  w += (size_t)NLAYERS * 4096 * 1024 * 2;
    unsigned short* Wout = (unsigned short*)w;  w += (size_t)NLAYERS * 1024 * 2048 * 2;
    unsigned short* Wxp  = (unsigned short*)w;  w += (size_t)NLAYERS * 256 * 2048 * 2;
    unsigned short* Xbf  = (unsigned short*)w;  w += (size_t)MROWS * 1024 * 2;
    unsigned short* P16  = (unsigned short*)w;  w += (size_t)MROWS * 2048 * 2;
    unsigned short* Z16  = (unsigned short*)w;  w += (size_t)MROWS * 2048 * 2;
    unsigned short* U16  = (unsigned short*)w;  w += (size_t)MROWS * 2048 * 2;
    float*          XDB  = (float*)w;

    hipMemcpyAsync(Xres, x_in, (size_t)MROWS * DMODEL * sizeof(float),
                   hipMemcpyDeviceToDevice, stream);

    cast_f2b_kernel<<<8192, 256, 0, stream>>>(Win, in_w, 2097152);
    cast_f2b_kernel<<<4096, 256, 0, stream>>>(Wout, out_w, 1048576);
    cast_xp_kernel<<<1024, 256, 0, stream>>>(Wxp, xp_w);
    cast_f2b_kernel<<<4096, 256, 0, stream>>>(Xbf, Xres, 1048576);

    for (int l = 0; l < NLAYERS; l++) {
        const unsigned short* winl = Win + (size_t)l * 4096 * 1024;
        const unsigned short* wol  = Wout + (size_t)l * 1024 * 2048;
        const unsigned short* wxl  = Wxp + (size_t)l * 256 * 2048;
        const float* cw  = conv_w + (size_t)l * DINNER * 4;
        const float* cb  = conv_b + (size_t)l * DINNER;
        const float* dtw = dtp_w  + (size_t)l * DINNER * DTRANK;
        const float* dtb = dtp_b  + (size_t)l * DINNER;
        const float* Al  = A_log  + (size_t)l * DINNER * DSTATE;
        const float* Dl  = D_skip + (size_t)l * DINNER;

        mgemm_kernel<0><<<dim3(64, 32), 256, 0, stream>>>(P16, Z16, Xbf, winl,
                                                          4096, DMODEL, DINNER);
        conv_silu_kernel<<<8192, 256, 0, stream>>>(U16, P16, cw, cb);
        mgemm_kernel<1><<<dim3(64, 2), 256, 0, stream>>>(XDB, nullptr, U16, wxl,
                                                         XDBW, DINNER, XDBW);
        gemm_delta_kernel<<<dim3(64, 16), 256, 0, stream>>>(P16, XDB, dtw, dtb,
                                                            MROWS, DINNER, DTRANK, XDBW, DINNER);
        scan_kernel<<<512, 256, 0, stream>>>(P16, U16, XDB, Al);
        gate_kernel<<<8192, 256, 0, stream>>>(Z16, P16, U16, Dl);
        mgemm_kernel<2><<<dim3(64, 8), 256, 0, stream>>>(Xres, Xbf, Z16, wol,
                                                         DMODEL, DINNER, DMODEL);
    }

    ln_kernel<<<2048, 256, 0, stream>>>(Xres, Xres, gam, bet);
}